// Round 11
// baseline (329.835 us; speedup 1.0000x reference)
//
#include <hip/hip_runtime.h>
#include <math.h>

#define NN 50000
#define NE 800000

typedef __attribute__((ext_vector_type(8))) short bf16x8;
typedef __attribute__((ext_vector_type(8))) unsigned short ushortx8;
typedef __attribute__((ext_vector_type(4))) float f32x4;

__device__ __forceinline__ float bf2f(ushort u) { return __uint_as_float(((unsigned)u) << 16); }
__device__ __forceinline__ ushort f2bf(float f) {
    unsigned b = __float_as_uint(f);
    return (ushort)((b + 0x7FFFu + ((b >> 16) & 1u)) >> 16);
}
__device__ __forceinline__ void load_lds16(const ushort* g, ushort* l) {
    __builtin_amdgcn_global_load_lds((const __attribute__((address_space(1))) unsigned int*)g,
                                     (__attribute__((address_space(3))) unsigned int*)l, 16, 0, 0);
}

// ---------------- fused x prep: x -> bf16, app_s/app_d dots, geo dots ----------------
__global__ void prep_x(const float* __restrict__ x, const float* __restrict__ W_app,
                       const float* __restrict__ coords, const float* __restrict__ Wg,
                       ushort* __restrict__ x_bf, float* __restrict__ app_s,
                       float* __restrict__ app_d, float* __restrict__ geo_s,
                       float* __restrict__ geo_d, int n) {
    int lane = threadIdx.x & 63, wid = threadIdx.x >> 6;
    int node = blockIdx.x * 4 + wid;
    if (node >= n) return;
    const float* xr = x + (size_t)node * 512 + lane * 8;
    float4 a = *reinterpret_cast<const float4*>(xr);
    float4 b = *reinterpret_cast<const float4*>(xr + 4);
    float4 ws0 = *reinterpret_cast<const float4*>(W_app + lane * 8);
    float4 ws1 = *reinterpret_cast<const float4*>(W_app + lane * 8 + 4);
    float4 wd0 = *reinterpret_cast<const float4*>(W_app + 512 + lane * 8);
    float4 wd1 = *reinterpret_cast<const float4*>(W_app + 512 + lane * 8 + 4);
    float ss = a.x * ws0.x + a.y * ws0.y + a.z * ws0.z + a.w * ws0.w
             + b.x * ws1.x + b.y * ws1.y + b.z * ws1.z + b.w * ws1.w;
    float dd = a.x * wd0.x + a.y * wd0.y + a.z * wd0.z + a.w * wd0.w
             + b.x * wd1.x + b.y * wd1.y + b.z * wd1.z + b.w * wd1.w;
    ushortx8 o;
    o.s0 = f2bf(a.x); o.s1 = f2bf(a.y); o.s2 = f2bf(a.z); o.s3 = f2bf(a.w);
    o.s4 = f2bf(b.x); o.s5 = f2bf(b.y); o.s6 = f2bf(b.z); o.s7 = f2bf(b.w);
    *reinterpret_cast<ushortx8*>(x_bf + (size_t)node * 512 + lane * 8) = o;
#pragma unroll
    for (int off = 32; off > 0; off >>= 1) {
        ss += __shfl_down(ss, off, 64);
        dd += __shfl_down(dd, off, 64);
    }
    if (lane == 0) {
        app_s[node] = ss; app_d[node] = dd;
        float4 c = *reinterpret_cast<const float4*>(coords + (size_t)node * 4);
        geo_s[node] = c.x * Wg[0] + c.y * Wg[1] + c.z * Wg[2] + c.w * Wg[3];
        geo_d[node] = c.x * Wg[4] + c.y * Wg[5] + c.z * Wg[6] + c.w * Wg[7];
    }
}

// ---------------- all three weight transposes in one launch ----------------
__global__ void cvt_wT_all(const float* __restrict__ W1, ushort* __restrict__ T1,
                           const float* __restrict__ W2, ushort* __restrict__ T2,
                           const float* __restrict__ W3, ushort* __restrict__ T3) {
    int idx = blockIdx.x * blockDim.x + threadIdx.x;
    if (idx < 131072) {
        int k = idx >> 8, n = idx & 255;
        T1[n * 512 + k] = f2bf(W1[idx]);
    } else if (idx < 163840) {
        int i = idx - 131072;
        int k = i >> 7, n = i & 127;
        T2[n * 256 + k] = f2bf(W2[i]);
    } else if (idx < 172032) {
        int i = idx - 163840;
        int k = i >> 6, n = i & 63;
        T3[n * 128 + k] = f2bf(W3[i]);
    }
}

// ---------------- CSR rank (the ONLY atomic pass: 800k) ----------------
__global__ void scatter_rank(const int* __restrict__ dst, int* __restrict__ cursor,
                             int* __restrict__ rank, int E) {
    int e = blockIdx.x * blockDim.x + threadIdx.x;
    if (e >= E) return;
    rank[e] = atomicAdd(&cursor[dst[e]], 1);
}

// ---------------- two-kernel scan: counts -> offsets ----------------
__global__ void scanA(const int* __restrict__ counts, int* __restrict__ btot, int n) {
    int b = blockIdx.x, tid = threadIdx.x;
    int lane = tid & 63, wid = tid >> 6;
    __shared__ int wsum[4];
    int i0 = b * 1024 + tid * 4;
    int s = 0;
#pragma unroll
    for (int k = 0; k < 4; ++k) { int i = i0 + k; if (i < n) s += counts[i]; }
#pragma unroll
    for (int off = 32; off > 0; off >>= 1) s += __shfl_down(s, off, 64);
    if (lane == 0) wsum[wid] = s;
    __syncthreads();
    if (tid == 0) btot[b] = wsum[0] + wsum[1] + wsum[2] + wsum[3];
}

__global__ void scanB(const int* __restrict__ counts, const int* __restrict__ btot,
                      int* __restrict__ offsets, int n, int total) {
    int b = blockIdx.x, tid = threadIdx.x;
    int lane = tid & 63, wid = tid >> 6;
    __shared__ int base_sh;
    __shared__ int wpre[4];
    if (tid < 64) {
        int v = (tid < b) ? btot[tid] : 0;
#pragma unroll
        for (int off = 32; off > 0; off >>= 1) v += __shfl_down(v, off, 64);
        if (tid == 0) base_sh = v;
    }
    int i0 = b * 1024 + tid * 4;
    int v0 = 0, v1 = 0, v2 = 0, v3 = 0;
    if (i0 + 3 < n) {
        int4 t = *reinterpret_cast<const int4*>(counts + i0);
        v0 = t.x; v1 = t.y; v2 = t.z; v3 = t.w;
    } else {
        if (i0 + 0 < n) v0 = counts[i0 + 0];
        if (i0 + 1 < n) v1 = counts[i0 + 1];
        if (i0 + 2 < n) v2 = counts[i0 + 2];
        if (i0 + 3 < n) v3 = counts[i0 + 3];
    }
    int t = v0 + v1 + v2 + v3;
    int inc = t;
#pragma unroll
    for (int off = 1; off < 64; off <<= 1) {
        int u = __shfl_up(inc, off, 64);
        if (lane >= off) inc += u;
    }
    if (lane == 63) wpre[wid] = inc;
    __syncthreads();
    if (tid == 0) {
        int s = 0;
#pragma unroll
        for (int w = 0; w < 4; ++w) { int u = wpre[w]; wpre[w] = s; s += u; }
    }
    __syncthreads();
    int ex = base_sh + wpre[wid] + (inc - t);
    if (i0 + 3 < n) {
        int4 o;
        o.x = ex; o.y = ex + v0; o.z = ex + v0 + v1; o.w = ex + v0 + v1 + v2;
        *reinterpret_cast<int4*>(offsets + i0) = o;
    } else {
        if (i0 + 0 < n) offsets[i0 + 0] = ex;
        if (i0 + 1 < n) offsets[i0 + 1] = ex + v0;
        if (i0 + 2 < n) offsets[i0 + 2] = ex + v0 + v1;
        if (i0 + 3 < n) offsets[i0 + 3] = ex + v0 + v1 + v2;
    }
    if (b == 0 && tid == 0) offsets[n] = total;
}

// ---------------- place: edge weight inline, packed int2 {src,w}, no atomics ----------------
__global__ void place_fused(const int* __restrict__ src, const int* __restrict__ dst,
                            const int* __restrict__ rank, const int* __restrict__ offsets,
                            const float* __restrict__ app_s, const float* __restrict__ app_d,
                            const float* __restrict__ geo_s, const float* __restrict__ geo_d,
                            const float* __restrict__ b_app, const float* __restrict__ b_geom,
                            const float* __restrict__ W_aff, const float* __restrict__ b_aff,
                            int2* __restrict__ pack, int E) {
    int e = blockIdx.x * blockDim.x + threadIdx.x;
    if (e >= E) return;
    int s = src[e], d = dst[e];
    float x1 = fmaxf(app_s[s] + app_d[d] + b_app[0], 0.f);
    float x2 = fmaxf(geo_s[s] + geo_d[d] + b_geom[0], 0.f);
    float w = fmaxf(x1 * W_aff[0] + x2 * W_aff[1] + b_aff[0], 0.f);
    int pos = offsets[d] + rank[e];
    pack[pos] = make_int2(s, __float_as_int(w));
}

// ---------------- deg/dinv from packed row sums ----------------
__global__ void deg_dinv_pk(const int2* __restrict__ pack, const int* __restrict__ offsets,
                            float* __restrict__ dinv, int n) {
    int i = blockIdx.x * blockDim.x + threadIdx.x;
    if (i >= n) return;
    int j0 = offsets[i], j1 = offsets[i + 1];
    float s = 1.f;
    for (int j = j0; j < j1; ++j) s += __int_as_float(pack[j].y);
    dinv[i] = rsqrtf(s);
}

// ---------------- phase 2: w2 into pack.y + dinv2 per row (no atomics) ----------------
__global__ void phase2_rows(int2* __restrict__ pack, const int* __restrict__ offsets,
                            const float* __restrict__ m_s, const float* __restrict__ m_d,
                            const float* __restrict__ b_m1, float* __restrict__ dinv2, int n) {
    int i = blockIdx.x * blockDim.x + threadIdx.x;
    if (i >= n) return;
    float md = m_d[i] + b_m1[0];
    int j0 = offsets[i], j1 = offsets[i + 1];
    float s = 1.f;
    for (int j = j0; j < j1; ++j) {
        int2 p = pack[j];
        float w = fmaxf(m_s[p.x] + md, 0.f);
        pack[j] = make_int2(p.x, __float_as_int(w));
        s += w;
    }
    dinv2[i] = rsqrtf(s);
}

// ---------------- MFMA bf16 GEMM: C[M,N] = rscale ⊙row (A[M,K] * BT[N,K]^T) ----------------
template <int WAVES_N, int MF, int NF, bool OUT_BF, bool RSCALE>
__global__ __launch_bounds__(256) void mfma_gemm(const ushort* __restrict__ A,
                                                 const ushort* __restrict__ BT,
                                                 void* __restrict__ Cout,
                                                 const float* __restrict__ rscale,
                                                 int M, int N, int K) {
    constexpr int WAVES_M = 4 / WAVES_N;
    constexpr int BM = WAVES_M * MF * 16;
    constexpr int BN = WAVES_N * NF * 16;
    constexpr int BK = 64;
    static_assert(BM == 128, "BM must be 128");
    __shared__ __align__(16) ushort As[BM * BK];
    __shared__ __align__(16) ushort Bs[BN * BK];
    const int tid = threadIdx.x;
    const int lane = tid & 63, wid = tid >> 6;
    const int wr = wid / WAVES_N, wc = wid % WAVES_N;
    const int m_blk = blockIdx.x * BM;
    const int n_blk = blockIdx.y * BN;

    const int slot = tid & 7;
    const int brow = tid >> 3;
    const int xslot = slot ^ (brow & 7);
    constexpr int ISS_A = BM / 32;
    constexpr int ISS_B = BN / 32;

    f32x4 acc[MF][NF];
#pragma unroll
    for (int i = 0; i < MF; ++i)
#pragma unroll
        for (int j = 0; j < NF; ++j) acc[i][j] = (f32x4){0.f, 0.f, 0.f, 0.f};

    const int frag_r_a = wr * (MF * 16) + (lane & 15);
    const int frag_r_b = wc * (NF * 16) + (lane & 15);
    const int frag_s = lane >> 4;

    const int nkt = K >> 6;
    for (int kt = 0; kt < nkt; ++kt) {
        const long kbase = (long)kt * 64;
#pragma unroll
        for (int i = 0; i < ISS_A; ++i) {
            int row = i * 32 + brow;
            const ushort* g = A + (long)(m_blk + row) * K + kbase + xslot * 8;
            load_lds16(g, As + i * 2048 + wid * 512);
        }
#pragma unroll
        for (int i = 0; i < ISS_B; ++i) {
            int row = i * 32 + brow;
            const ushort* g = BT + (long)(n_blk + row) * K + kbase + xslot * 8;
            load_lds16(g, Bs + i * 2048 + wid * 512);
        }
        asm volatile("s_waitcnt vmcnt(0)" ::: "memory");
        __syncthreads();
#pragma unroll
        for (int ks = 0; ks < 2; ++ks) {
            bf16x8 av[MF], bv[NF];
#pragma unroll
            for (int mf = 0; mf < MF; ++mf) {
                int r = frag_r_a + mf * 16;
                int s = ks * 4 + frag_s;
                av[mf] = *reinterpret_cast<const bf16x8*>(As + r * BK + ((s ^ (r & 7)) << 3));
            }
#pragma unroll
            for (int nf = 0; nf < NF; ++nf) {
                int r = frag_r_b + nf * 16;
                int s = ks * 4 + frag_s;
                bv[nf] = *reinterpret_cast<const bf16x8*>(Bs + r * BK + ((s ^ (r & 7)) << 3));
            }
#pragma unroll
            for (int mf = 0; mf < MF; ++mf)
#pragma unroll
                for (int nf = 0; nf < NF; ++nf)
                    acc[mf][nf] = __builtin_amdgcn_mfma_f32_16x16x32_bf16(av[mf], bv[nf], acc[mf][nf], 0, 0, 0);
        }
        __syncthreads();
    }
    const int col0 = n_blk + wc * NF * 16 + (lane & 15);
    const int row0 = m_blk + wr * MF * 16 + ((lane >> 4) << 2);
#pragma unroll
    for (int mf = 0; mf < MF; ++mf) {
#pragma unroll
        for (int r = 0; r < 4; ++r) {
            int row = row0 + mf * 16 + r;
            if (row < M) {
                float sc = RSCALE ? rscale[row] : 1.f;
#pragma unroll
                for (int nf = 0; nf < NF; ++nf) {
                    float v = acc[mf][nf][r] * sc;
                    if (OUT_BF)
                        ((ushort*)Cout)[(long)row * N + col0 + nf * 16] = f2bf(v);
                    else
                        ((float*)Cout)[(long)row * N + col0 + nf * 16] = v;
                }
            }
        }
    }
}

// ---------------- GCN aggregation on pre-scaled table g = dinv ⊙ (X@W) ----------------
// Wave per node, full-row gathers (ushort4/lane for C=256, ushort2 for C=128).
// 16-deep + 8-deep + tail unroll for deep MLP. NT loads on the pack stream,
// NT stores on the output (both streamed once; keeps the gather table in L2).
// out[node] = bf16( dn*(g[n] + sum_j w_j * g[src_j]) + bias ) ;
// FUSE: m_s/m_d = out_row . W_m1 halves (full-wave shfl reduce).
template <int C, bool RELU, bool FUSE>
__global__ void conv_agg_pk(const ushort* __restrict__ g, const float* __restrict__ dinv,
                            const int2* __restrict__ pack, const int* __restrict__ offsets,
                            const float* __restrict__ bias, ushort* __restrict__ out,
                            const float* __restrict__ W_m1, float* __restrict__ m_s,
                            float* __restrict__ m_d, int n) {
    constexpr int V = C / 64;  // 4 or 2
    int lane = threadIdx.x & 63, wid = threadIdx.x >> 6;
    int node = blockIdx.x * (blockDim.x >> 6) + wid;
    if (node >= n) return;
    float dn = dinv[node];
    float acc[V];
    {
        const ushort* hn = g + (size_t)node * C + lane * V;
        if constexpr (V == 4) {
            ushort4 v = *reinterpret_cast<const ushort4*>(hn);
            acc[0] = bf2f(v.x); acc[1] = bf2f(v.y); acc[2] = bf2f(v.z); acc[3] = bf2f(v.w);
        } else {
            ushort2 v = *reinterpret_cast<const ushort2*>(hn);
            acc[0] = bf2f(v.x); acc[1] = bf2f(v.y);
        }
    }
    int j0 = offsets[node], j1 = offsets[node + 1];
    int j = j0;
    const unsigned long long* pku = reinterpret_cast<const unsigned long long*>(pack);
    for (; j + 16 <= j1; j += 16) {
        unsigned long long p[16];
#pragma unroll
        for (int q = 0; q < 16; ++q) p[q] = __builtin_nontemporal_load(pku + j + q);
        if constexpr (V == 4) {
            ushort4 v[16];
#pragma unroll
            for (int q = 0; q < 16; ++q)
                v[q] = *reinterpret_cast<const ushort4*>(g + (size_t)(unsigned)(p[q] & 0xFFFFFFFFu) * C + lane * 4);
#pragma unroll
            for (int q = 0; q < 16; ++q) {
                float a = __uint_as_float((unsigned)(p[q] >> 32));
                acc[0] += a * bf2f(v[q].x);
                acc[1] += a * bf2f(v[q].y);
                acc[2] += a * bf2f(v[q].z);
                acc[3] += a * bf2f(v[q].w);
            }
        } else {
            ushort2 v[16];
#pragma unroll
            for (int q = 0; q < 16; ++q)
                v[q] = *reinterpret_cast<const ushort2*>(g + (size_t)(unsigned)(p[q] & 0xFFFFFFFFu) * C + lane * 2);
#pragma unroll
            for (int q = 0; q < 16; ++q) {
                float a = __uint_as_float((unsigned)(p[q] >> 32));
                acc[0] += a * bf2f(v[q].x);
                acc[1] += a * bf2f(v[q].y);
            }
        }
    }
    for (; j + 8 <= j1; j += 8) {
        unsigned long long p[8];
#pragma unroll
        for (int q = 0; q < 8; ++q) p[q] = __builtin_nontemporal_load(pku + j + q);
        if constexpr (V == 4) {
            ushort4 v[8];
#pragma unroll
            for (int q = 0; q < 8; ++q)
                v[q] = *reinterpret_cast<const ushort4*>(g + (size_t)(unsigned)(p[q] & 0xFFFFFFFFu) * C + lane * 4);
#pragma unroll
            for (int q = 0; q < 8; ++q) {
                float a = __uint_as_float((unsigned)(p[q] >> 32));
                acc[0] += a * bf2f(v[q].x);
                acc[1] += a * bf2f(v[q].y);
                acc[2] += a * bf2f(v[q].z);
                acc[3] += a * bf2f(v[q].w);
            }
        } else {
            ushort2 v[8];
#pragma unroll
            for (int q = 0; q < 8; ++q)
                v[q] = *reinterpret_cast<const ushort2*>(g + (size_t)(unsigned)(p[q] & 0xFFFFFFFFu) * C + lane * 2);
#pragma unroll
            for (int q = 0; q < 8; ++q) {
                float a = __uint_as_float((unsigned)(p[q] >> 32));
                acc[0] += a * bf2f(v[q].x);
                acc[1] += a * bf2f(v[q].y);
            }
        }
    }
    for (; j < j1; ++j) {
        int2 p = pack[j];
        float a = __int_as_float(p.y);
        const ushort* hs = g + (size_t)p.x * C + lane * V;
        if constexpr (V == 4) {
            ushort4 v = *reinterpret_cast<const ushort4*>(hs);
            acc[0] += a * bf2f(v.x); acc[1] += a * bf2f(v.y);
            acc[2] += a * bf2f(v.z); acc[3] += a * bf2f(v.w);
        } else {
            ushort2 v = *reinterpret_cast<const ushort2*>(hs);
            acc[0] += a * bf2f(v.x); acc[1] += a * bf2f(v.y);
        }
    }
    const float* bp = bias + lane * V;
    if constexpr (V == 4) {
        float o0 = acc[0] * dn + bp[0], o1 = acc[1] * dn + bp[1];
        float o2 = acc[2] * dn + bp[2], o3 = acc[3] * dn + bp[3];
        if (RELU) { o0 = fmaxf(o0, 0.f); o1 = fmaxf(o1, 0.f); o2 = fmaxf(o2, 0.f); o3 = fmaxf(o3, 0.f); }
        unsigned lo = (unsigned)f2bf(o0) | ((unsigned)f2bf(o1) << 16);
        unsigned hi = (unsigned)f2bf(o2) | ((unsigned)f2bf(o3) << 16);
        unsigned long long st = (unsigned long long)lo | ((unsigned long long)hi << 32);
        __builtin_nontemporal_store(st,
            reinterpret_cast<unsigned long long*>(out + (size_t)node * C + lane * 4));
        if constexpr (FUSE) {
            float4 wms = *reinterpret_cast<const float4*>(W_m1 + lane * 4);
            float4 wmd = *reinterpret_cast<const float4*>(W_m1 + C + lane * 4);
            float ms = o0 * wms.x + o1 * wms.y + o2 * wms.z + o3 * wms.w;
            float md = o0 * wmd.x + o1 * wmd.y + o2 * wmd.z + o3 * wmd.w;
#pragma unroll
            for (int off = 32; off > 0; off >>= 1) {
                ms += __shfl_down(ms, off, 64);
                md += __shfl_down(md, off, 64);
            }
            if (lane == 0) { m_s[node] = ms; m_d[node] = md; }
        }
    } else {
        float o0 = acc[0] * dn + bp[0], o1 = acc[1] * dn + bp[1];
        if (RELU) { o0 = fmaxf(o0, 0.f); o1 = fmaxf(o1, 0.f); }
        unsigned st = (unsigned)f2bf(o0) | ((unsigned)f2bf(o1) << 16);
        __builtin_nontemporal_store(st,
            reinterpret_cast<unsigned*>(out + (size_t)node * C + lane * 2));
    }
}

// ---------------- final pairwise classifier on bf16 y1 = out2 @ W_f1 ----------------
__global__ __launch_bounds__(256) void final_edge(const ushort* __restrict__ y1,
                                                  const int* __restrict__ ea,
                                                  const int* __restrict__ eb,
                                                  const float* __restrict__ b_f1,
                                                  const float* __restrict__ W_f2,
                                                  const float* __restrict__ b_f2,
                                                  float* __restrict__ out, int E) {
    int lane = threadIdx.x & 63, wid = threadIdx.x >> 6;
    int sub = lane >> 3, k8 = lane & 7;
    int wave = blockIdx.x * 4 + wid;
    int e = wave * 8 + sub;
    if (e >= E) return;
    float4 bf1a = *reinterpret_cast<const float4*>(b_f1 + k8 * 8);
    float4 bf1b = *reinterpret_cast<const float4*>(b_f1 + k8 * 8 + 4);
    float4 wf2a = *reinterpret_cast<const float4*>(W_f2 + k8 * 8);
    float4 wf2b = *reinterpret_cast<const float4*>(W_f2 + k8 * 8 + 4);
    int a = ea[e], b = eb[e];
    ushortx8 va = *reinterpret_cast<const ushortx8*>(y1 + (size_t)a * 64 + k8 * 8);
    ushortx8 vb = *reinterpret_cast<const ushortx8*>(y1 + (size_t)b * 64 + k8 * 8);
    float p = fmaxf(bf2f(va.s0) - bf2f(vb.s0) + bf1a.x, 0.f) * wf2a.x
            + fmaxf(bf2f(va.s1) - bf2f(vb.s1) + bf1a.y, 0.f) * wf2a.y
            + fmaxf(bf2f(va.s2) - bf2f(vb.s2) + bf1a.z, 0.f) * wf2a.z
            + fmaxf(bf2f(va.s3) - bf2f(vb.s3) + bf1a.w, 0.f) * wf2a.w
            + fmaxf(bf2f(va.s4) - bf2f(vb.s4) + bf1b.x, 0.f) * wf2b.x
            + fmaxf(bf2f(va.s5) - bf2f(vb.s5) + bf1b.y, 0.f) * wf2b.y
            + fmaxf(bf2f(va.s6) - bf2f(vb.s6) + bf1b.z, 0.f) * wf2b.z
            + fmaxf(bf2f(va.s7) - bf2f(vb.s7) + bf1b.w, 0.f) * wf2b.w;
    p += __shfl_xor(p, 1, 64);
    p += __shfl_xor(p, 2, 64);
    p += __shfl_xor(p, 4, 64);
    if (k8 == 0) out[e] = 1.f / (1.f + expf(-(p + b_f2[0])));
}

extern "C" void kernel_launch(void* const* d_in, const int* in_sizes, int n_in,
                              void* d_out, int out_size, void* d_ws, size_t ws_size,
                              hipStream_t stream) {
    const float* x      = (const float*)d_in[0];
    const float* coords = (const float*)d_in[1];
    const float* W_app  = (const float*)d_in[2];
    const float* b_app  = (const float*)d_in[3];
    const float* W_geom = (const float*)d_in[4];
    const float* b_geom = (const float*)d_in[5];
    const float* W_aff  = (const float*)d_in[6];
    const float* b_aff  = (const float*)d_in[7];
    const float* W_c1   = (const float*)d_in[8];
    const float* b_c1   = (const float*)d_in[9];
    const float* W_m1   = (const float*)d_in[10];
    const float* b_m1   = (const float*)d_in[11];
    const float* W_c2   = (const float*)d_in[12];
    const float* b_c2   = (const float*)d_in[13];
    const float* W_f1   = (const float*)d_in[14];
    const float* b_f1   = (const float*)d_in[15];
    const float* W_f2   = (const float*)d_in[16];
    const float* b_f2   = (const float*)d_in[17];
    const int*   e1     = (const int*)d_in[18];
    const int*   e2     = (const int*)d_in[19];
    float* out = (float*)d_out;

    const int N = NN;
    const int E = NE;
    const int MP = 50048;  // 391*128
    const int* src1 = e1;
    const int* dst1 = e1 + E;
    const int* e2a = e2;
    const int* e2b = e2 + E;

    char* ws = (char*)d_ws;
    size_t off = 0;
    auto alloc = [&](size_t bytes) -> void* {
        void* p = ws + off;
        off += (bytes + 255) & ~(size_t)255;
        return p;
    };
    float* app_s  = (float*)alloc((size_t)N * 4);
    float* app_d  = (float*)alloc((size_t)N * 4);
    float* geo_s  = (float*)alloc((size_t)N * 4);
    float* geo_d  = (float*)alloc((size_t)N * 4);
    float* m_s    = (float*)alloc((size_t)N * 4);
    float* m_d    = (float*)alloc((size_t)N * 4);
    float* dinv1  = (float*)alloc((size_t)N * 4);
    float* dinv2  = (float*)alloc((size_t)N * 4);
    int* cursor   = (int*)alloc((size_t)N * 4);
    int* offsets  = (int*)alloc((size_t)(N + 1) * 4);
    int* btot     = (int*)alloc((size_t)64 * 4);
    int* rank     = (int*)alloc((size_t)E * 4);
    int2* pack    = (int2*)alloc((size_t)E * 8);   // packed {src, w:f32}
    ushort* wc1T  = (ushort*)alloc((size_t)256 * 512 * 2);
    ushort* wc2T  = (ushort*)alloc((size_t)128 * 256 * 2);
    ushort* wf1T  = (ushort*)alloc((size_t)64 * 128 * 2);
    ushort* x_bf  = (ushort*)alloc((size_t)MP * 512 * 2);  // 51.25 MB
    ushort* h_bf  = (ushort*)alloc((size_t)MP * 256 * 2);  // 25.62 MB
    // overlays:
    ushort* out1b = x_bf;                    // [MP][256] (x_bf dead after gemm1)
    ushort* h2b   = h_bf;                    // [N][128]  (h_bf dead after conv1)
    ushort* out2b = h_bf + (size_t)N * 128;  // [MP][128]
    ushort* y1b   = x_bf;                    // [MP][64]  (out1b dead after gemm2)

    int gN = (N + 255) / 256;
    int gE = (E + 255) / 256;
    int gW = (N + 3) / 4;
    int nb = (N + 1023) / 1024;   // 49

    hipMemsetAsync(cursor, 0, (size_t)N * 4, stream);
    prep_x<<<gW, 256, 0, stream>>>(x, W_app, coords, W_geom, x_bf, app_s, app_d,
                                   geo_s, geo_d, N);
    cvt_wT_all<<<672, 256, 0, stream>>>(W_c1, wc1T, W_c2, wc2T, W_f1, wf1T);

    // CSR build: one atomic pass, two-kernel scan, non-atomic place -> packed int2
    scatter_rank<<<gE, 256, 0, stream>>>(dst1, cursor, rank, E);
    scanA<<<nb, 256, 0, stream>>>(cursor, btot, N);
    scanB<<<nb, 256, 0, stream>>>(cursor, btot, offsets, N, E);
    place_fused<<<gE, 256, 0, stream>>>(src1, dst1, rank, offsets, app_s, app_d, geo_s, geo_d,
                                        b_app, b_geom, W_aff, b_aff, pack, E);
    deg_dinv_pk<<<gN, 256, 0, stream>>>(pack, offsets, dinv1, N);

    // g1 = bf16(dinv1 ⊙ (x @ W_c1))
    mfma_gemm<2, 4, 4, true, true><<<dim3(MP / 128, 2), 256, 0, stream>>>(
        x_bf, wc1T, h_bf, dinv1, N, 256, 512);
    // out1b = relu(dn*(g1[n]+Σ w g1[src]) + b_c1) — wave/node, 16-deep MLP; fused m dots
    conv_agg_pk<256, true, true><<<gW, 256, 0, stream>>>(
        h_bf, dinv1, pack, offsets, b_c1, out1b, W_m1, m_s, m_d, N);

    // phase-2 edge weights into pack.y + dinv2
    phase2_rows<<<gN, 256, 0, stream>>>(pack, offsets, m_s, m_d, b_m1, dinv2, N);

    // g2 = bf16(dinv2 ⊙ (out1b @ W_c2))
    mfma_gemm<2, 4, 4, true, true><<<dim3(MP / 128, 1), 256, 0, stream>>>(
        out1b, wc2T, h2b, dinv2, N, 128, 256);
    // out2b = dn*(g2[n]+Σ w2 g2[src]) + b_c2 — wave/node
    conv_agg_pk<128, false, false><<<gW, 256, 0, stream>>>(
        h2b, dinv2, pack, offsets, b_c2, out2b, nullptr, nullptr, nullptr, N);

    // y1b = bf16(out2b @ W_f1)
    mfma_gemm<1, 2, 4, true, false><<<dim3(MP / 128, 1), 256, 0, stream>>>(
        out2b, wf1T, y1b, nullptr, N, 64, 128);

    // final pairwise classifier (8 lanes/edge)
    final_edge<<<E / 32, 256, 0, stream>>>(y1b, e2a, e2b, b_f1, W_f2, b_f2, out, E);
}

// Round 12
// 307.562 us; speedup vs baseline: 1.0724x; 1.0724x over previous
//
#include <hip/hip_runtime.h>
#include <math.h>

#define NN 50000
#define NE 800000

typedef __attribute__((ext_vector_type(8))) short bf16x8;
typedef __attribute__((ext_vector_type(8))) unsigned short ushortx8;
typedef __attribute__((ext_vector_type(4))) float f32x4;

__device__ __forceinline__ float bf2f(ushort u) { return __uint_as_float(((unsigned)u) << 16); }
__device__ __forceinline__ ushort f2bf(float f) {
    unsigned b = __float_as_uint(f);
    return (ushort)((b + 0x7FFFu + ((b >> 16) & 1u)) >> 16);
}
__device__ __forceinline__ void load_lds16(const ushort* g, ushort* l) {
    __builtin_amdgcn_global_load_lds((const __attribute__((address_space(1))) unsigned int*)g,
                                     (__attribute__((address_space(3))) unsigned int*)l, 16, 0, 0);
}

// ---------------- fused x prep: x -> bf16, app_s/app_d dots, geo dots ----------------
__global__ void prep_x(const float* __restrict__ x, const float* __restrict__ W_app,
                       const float* __restrict__ coords, const float* __restrict__ Wg,
                       ushort* __restrict__ x_bf, float* __restrict__ app_s,
                       float* __restrict__ app_d, float* __restrict__ geo_s,
                       float* __restrict__ geo_d, int n) {
    int lane = threadIdx.x & 63, wid = threadIdx.x >> 6;
    int node = blockIdx.x * 4 + wid;
    if (node >= n) return;
    const float* xr = x + (size_t)node * 512 + lane * 8;
    float4 a = *reinterpret_cast<const float4*>(xr);
    float4 b = *reinterpret_cast<const float4*>(xr + 4);
    float4 ws0 = *reinterpret_cast<const float4*>(W_app + lane * 8);
    float4 ws1 = *reinterpret_cast<const float4*>(W_app + lane * 8 + 4);
    float4 wd0 = *reinterpret_cast<const float4*>(W_app + 512 + lane * 8);
    float4 wd1 = *reinterpret_cast<const float4*>(W_app + 512 + lane * 8 + 4);
    float ss = a.x * ws0.x + a.y * ws0.y + a.z * ws0.z + a.w * ws0.w
             + b.x * ws1.x + b.y * ws1.y + b.z * ws1.z + b.w * ws1.w;
    float dd = a.x * wd0.x + a.y * wd0.y + a.z * wd0.z + a.w * wd0.w
             + b.x * wd1.x + b.y * wd1.y + b.z * wd1.z + b.w * wd1.w;
    ushortx8 o;
    o.s0 = f2bf(a.x); o.s1 = f2bf(a.y); o.s2 = f2bf(a.z); o.s3 = f2bf(a.w);
    o.s4 = f2bf(b.x); o.s5 = f2bf(b.y); o.s6 = f2bf(b.z); o.s7 = f2bf(b.w);
    *reinterpret_cast<ushortx8*>(x_bf + (size_t)node * 512 + lane * 8) = o;
#pragma unroll
    for (int off = 32; off > 0; off >>= 1) {
        ss += __shfl_down(ss, off, 64);
        dd += __shfl_down(dd, off, 64);
    }
    if (lane == 0) {
        app_s[node] = ss; app_d[node] = dd;
        float4 c = *reinterpret_cast<const float4*>(coords + (size_t)node * 4);
        geo_s[node] = c.x * Wg[0] + c.y * Wg[1] + c.z * Wg[2] + c.w * Wg[3];
        geo_d[node] = c.x * Wg[4] + c.y * Wg[5] + c.z * Wg[6] + c.w * Wg[7];
    }
}

// ---------------- all three weight transposes in one launch ----------------
__global__ void cvt_wT_all(const float* __restrict__ W1, ushort* __restrict__ T1,
                           const float* __restrict__ W2, ushort* __restrict__ T2,
                           const float* __restrict__ W3, ushort* __restrict__ T3) {
    int idx = blockIdx.x * blockDim.x + threadIdx.x;
    if (idx < 131072) {
        int k = idx >> 8, n = idx & 255;
        T1[n * 512 + k] = f2bf(W1[idx]);
    } else if (idx < 163840) {
        int i = idx - 131072;
        int k = i >> 7, n = i & 127;
        T2[n * 256 + k] = f2bf(W2[i]);
    } else if (idx < 172032) {
        int i = idx - 163840;
        int k = i >> 6, n = i & 63;
        T3[n * 128 + k] = f2bf(W3[i]);
    }
}

// ---------------- CSR rank (the ONLY atomic pass: 800k) ----------------
__global__ void scatter_rank(const int* __restrict__ dst, int* __restrict__ cursor,
                             int* __restrict__ rank, int E) {
    int e = blockIdx.x * blockDim.x + threadIdx.x;
    if (e >= E) return;
    rank[e] = atomicAdd(&cursor[dst[e]], 1);
}

// ---------------- two-kernel scan: counts -> offsets ----------------
__global__ void scanA(const int* __restrict__ counts, int* __restrict__ btot, int n) {
    int b = blockIdx.x, tid = threadIdx.x;
    int lane = tid & 63, wid = tid >> 6;
    __shared__ int wsum[4];
    int i0 = b * 1024 + tid * 4;
    int s = 0;
#pragma unroll
    for (int k = 0; k < 4; ++k) { int i = i0 + k; if (i < n) s += counts[i]; }
#pragma unroll
    for (int off = 32; off > 0; off >>= 1) s += __shfl_down(s, off, 64);
    if (lane == 0) wsum[wid] = s;
    __syncthreads();
    if (tid == 0) btot[b] = wsum[0] + wsum[1] + wsum[2] + wsum[3];
}

__global__ void scanB(const int* __restrict__ counts, const int* __restrict__ btot,
                      int* __restrict__ offsets, int n, int total) {
    int b = blockIdx.x, tid = threadIdx.x;
    int lane = tid & 63, wid = tid >> 6;
    __shared__ int base_sh;
    __shared__ int wpre[4];
    if (tid < 64) {
        int v = (tid < b) ? btot[tid] : 0;
#pragma unroll
        for (int off = 32; off > 0; off >>= 1) v += __shfl_down(v, off, 64);
        if (tid == 0) base_sh = v;
    }
    int i0 = b * 1024 + tid * 4;
    int v0 = 0, v1 = 0, v2 = 0, v3 = 0;
    if (i0 + 3 < n) {
        int4 t = *reinterpret_cast<const int4*>(counts + i0);
        v0 = t.x; v1 = t.y; v2 = t.z; v3 = t.w;
    } else {
        if (i0 + 0 < n) v0 = counts[i0 + 0];
        if (i0 + 1 < n) v1 = counts[i0 + 1];
        if (i0 + 2 < n) v2 = counts[i0 + 2];
        if (i0 + 3 < n) v3 = counts[i0 + 3];
    }
    int t = v0 + v1 + v2 + v3;
    int inc = t;
#pragma unroll
    for (int off = 1; off < 64; off <<= 1) {
        int u = __shfl_up(inc, off, 64);
        if (lane >= off) inc += u;
    }
    if (lane == 63) wpre[wid] = inc;
    __syncthreads();
    if (tid == 0) {
        int s = 0;
#pragma unroll
        for (int w = 0; w < 4; ++w) { int u = wpre[w]; wpre[w] = s; s += u; }
    }
    __syncthreads();
    int ex = base_sh + wpre[wid] + (inc - t);
    if (i0 + 3 < n) {
        int4 o;
        o.x = ex; o.y = ex + v0; o.z = ex + v0 + v1; o.w = ex + v0 + v1 + v2;
        *reinterpret_cast<int4*>(offsets + i0) = o;
    } else {
        if (i0 + 0 < n) offsets[i0 + 0] = ex;
        if (i0 + 1 < n) offsets[i0 + 1] = ex + v0;
        if (i0 + 2 < n) offsets[i0 + 2] = ex + v0 + v1;
        if (i0 + 3 < n) offsets[i0 + 3] = ex + v0 + v1 + v2;
    }
    if (b == 0 && tid == 0) offsets[n] = total;
}

// ---------------- place: edge weight inline, two streams {src},{w}, no atomics ----------------
__global__ void place_fused(const int* __restrict__ src, const int* __restrict__ dst,
                            const int* __restrict__ rank, const int* __restrict__ offsets,
                            const float* __restrict__ app_s, const float* __restrict__ app_d,
                            const float* __restrict__ geo_s, const float* __restrict__ geo_d,
                            const float* __restrict__ b_app, const float* __restrict__ b_geom,
                            const float* __restrict__ W_aff, const float* __restrict__ b_aff,
                            int* __restrict__ csr_src, float* __restrict__ csr_w, int E) {
    int e = blockIdx.x * blockDim.x + threadIdx.x;
    if (e >= E) return;
    int s = src[e], d = dst[e];
    float x1 = fmaxf(app_s[s] + app_d[d] + b_app[0], 0.f);
    float x2 = fmaxf(geo_s[s] + geo_d[d] + b_geom[0], 0.f);
    float w = fmaxf(x1 * W_aff[0] + x2 * W_aff[1] + b_aff[0], 0.f);
    int pos = offsets[d] + rank[e];
    csr_src[pos] = s;
    csr_w[pos] = w;
}

// ---------------- deg/dinv from row sums ----------------
__global__ void deg_dinv(const float* __restrict__ w, const int* __restrict__ offsets,
                         float* __restrict__ dinv, int n) {
    int i = blockIdx.x * blockDim.x + threadIdx.x;
    if (i >= n) return;
    int j0 = offsets[i], j1 = offsets[i + 1];
    float s = 1.f;
    for (int j = j0; j < j1; ++j) s += w[j];
    dinv[i] = rsqrtf(s);
}

// ---------------- phase 2: w2 into csr_w + dinv2 per row (no atomics) ----------------
__global__ void phase2_rows(const int* __restrict__ csr_src, float* __restrict__ csr_w,
                            const int* __restrict__ offsets,
                            const float* __restrict__ m_s, const float* __restrict__ m_d,
                            const float* __restrict__ b_m1, float* __restrict__ dinv2, int n) {
    int i = blockIdx.x * blockDim.x + threadIdx.x;
    if (i >= n) return;
    float md = m_d[i] + b_m1[0];
    int j0 = offsets[i], j1 = offsets[i + 1];
    float s = 1.f;
    for (int j = j0; j < j1; ++j) {
        float w = fmaxf(m_s[csr_src[j]] + md, 0.f);
        csr_w[j] = w;
        s += w;
    }
    dinv2[i] = rsqrtf(s);
}

// ---------------- MFMA bf16 GEMM: C[M,N] = rscale ⊙row (A[M,K] * BT[N,K]^T) ----------------
template <int WAVES_N, int MF, int NF, bool OUT_BF, bool RSCALE>
__global__ __launch_bounds__(256) void mfma_gemm(const ushort* __restrict__ A,
                                                 const ushort* __restrict__ BT,
                                                 void* __restrict__ Cout,
                                                 const float* __restrict__ rscale,
                                                 int M, int N, int K) {
    constexpr int WAVES_M = 4 / WAVES_N;
    constexpr int BM = WAVES_M * MF * 16;
    constexpr int BN = WAVES_N * NF * 16;
    constexpr int BK = 64;
    static_assert(BM == 128, "BM must be 128");
    __shared__ __align__(16) ushort As[BM * BK];
    __shared__ __align__(16) ushort Bs[BN * BK];
    const int tid = threadIdx.x;
    const int lane = tid & 63, wid = tid >> 6;
    const int wr = wid / WAVES_N, wc = wid % WAVES_N;
    const int m_blk = blockIdx.x * BM;
    const int n_blk = blockIdx.y * BN;

    const int slot = tid & 7;
    const int brow = tid >> 3;
    const int xslot = slot ^ (brow & 7);
    constexpr int ISS_A = BM / 32;
    constexpr int ISS_B = BN / 32;

    f32x4 acc[MF][NF];
#pragma unroll
    for (int i = 0; i < MF; ++i)
#pragma unroll
        for (int j = 0; j < NF; ++j) acc[i][j] = (f32x4){0.f, 0.f, 0.f, 0.f};

    const int frag_r_a = wr * (MF * 16) + (lane & 15);
    const int frag_r_b = wc * (NF * 16) + (lane & 15);
    const int frag_s = lane >> 4;

    const int nkt = K >> 6;
    for (int kt = 0; kt < nkt; ++kt) {
        const long kbase = (long)kt * 64;
#pragma unroll
        for (int i = 0; i < ISS_A; ++i) {
            int row = i * 32 + brow;
            const ushort* g = A + (long)(m_blk + row) * K + kbase + xslot * 8;
            load_lds16(g, As + i * 2048 + wid * 512);
        }
#pragma unroll
        for (int i = 0; i < ISS_B; ++i) {
            int row = i * 32 + brow;
            const ushort* g = BT + (long)(n_blk + row) * K + kbase + xslot * 8;
            load_lds16(g, Bs + i * 2048 + wid * 512);
        }
        asm volatile("s_waitcnt vmcnt(0)" ::: "memory");
        __syncthreads();
#pragma unroll
        for (int ks = 0; ks < 2; ++ks) {
            bf16x8 av[MF], bv[NF];
#pragma unroll
            for (int mf = 0; mf < MF; ++mf) {
                int r = frag_r_a + mf * 16;
                int s = ks * 4 + frag_s;
                av[mf] = *reinterpret_cast<const bf16x8*>(As + r * BK + ((s ^ (r & 7)) << 3));
            }
#pragma unroll
            for (int nf = 0; nf < NF; ++nf) {
                int r = frag_r_b + nf * 16;
                int s = ks * 4 + frag_s;
                bv[nf] = *reinterpret_cast<const bf16x8*>(Bs + r * BK + ((s ^ (r & 7)) << 3));
            }
#pragma unroll
            for (int mf = 0; mf < MF; ++mf)
#pragma unroll
                for (int nf = 0; nf < NF; ++nf)
                    acc[mf][nf] = __builtin_amdgcn_mfma_f32_16x16x32_bf16(av[mf], bv[nf], acc[mf][nf], 0, 0, 0);
        }
        __syncthreads();
    }
    const int col0 = n_blk + wc * NF * 16 + (lane & 15);
    const int row0 = m_blk + wr * MF * 16 + ((lane >> 4) << 2);
#pragma unroll
    for (int mf = 0; mf < MF; ++mf) {
#pragma unroll
        for (int r = 0; r < 4; ++r) {
            int row = row0 + mf * 16 + r;
            if (row < M) {
                float sc = RSCALE ? rscale[row] : 1.f;
#pragma unroll
                for (int nf = 0; nf < NF; ++nf) {
                    float v = acc[mf][nf][r] * sc;
                    if (OUT_BF)
                        ((ushort*)Cout)[(long)row * N + col0 + nf * 16] = f2bf(v);
                    else
                        ((float*)Cout)[(long)row * N + col0 + nf * 16] = v;
                }
            }
        }
    }
}

// ---------------- GCN aggregation on pre-scaled table g = dinv ⊙ (X@W) ----------------
// Wave per node, full-row gathers (ushort4/lane for C=256, ushort2 for C=128),
// two-stream coefficients (csr_src ints + csr_w floats), 8-deep unroll — the
// r4-measured best configuration (62 µs @ 189 MB, VGPR 24).
// out[node] = bf16( dn*(g[n] + sum_j w_j * g[src_j]) + bias ) ;
// FUSE: m_s/m_d = out_row . W_m1 halves (full-wave shfl reduce).
template <int C, bool RELU, bool FUSE>
__global__ void conv_agg(const ushort* __restrict__ g, const float* __restrict__ dinv,
                         const int* __restrict__ csr_src, const float* __restrict__ csr_w,
                         const int* __restrict__ offsets,
                         const float* __restrict__ bias, ushort* __restrict__ out,
                         const float* __restrict__ W_m1, float* __restrict__ m_s,
                         float* __restrict__ m_d, int n) {
    constexpr int V = C / 64;  // 4 or 2
    int lane = threadIdx.x & 63, wid = threadIdx.x >> 6;
    int node = blockIdx.x * (blockDim.x >> 6) + wid;
    if (node >= n) return;
    float dn = dinv[node];
    float acc[V];
    {
        const ushort* hn = g + (size_t)node * C + lane * V;
        if constexpr (V == 4) {
            ushort4 v = *reinterpret_cast<const ushort4*>(hn);
            acc[0] = bf2f(v.x); acc[1] = bf2f(v.y); acc[2] = bf2f(v.z); acc[3] = bf2f(v.w);
        } else {
            ushort2 v = *reinterpret_cast<const ushort2*>(hn);
            acc[0] = bf2f(v.x); acc[1] = bf2f(v.y);
        }
    }
    int j0 = offsets[node], j1 = offsets[node + 1];
    int j = j0;
    for (; j + 8 <= j1; j += 8) {
        int s[8]; float a[8];
#pragma unroll
        for (int q = 0; q < 8; ++q) s[q] = csr_src[j + q];
#pragma unroll
        for (int q = 0; q < 8; ++q) a[q] = csr_w[j + q];
        if constexpr (V == 4) {
            ushort4 v[8];
#pragma unroll
            for (int q = 0; q < 8; ++q)
                v[q] = *reinterpret_cast<const ushort4*>(g + (size_t)s[q] * C + lane * 4);
#pragma unroll
            for (int q = 0; q < 8; ++q) {
                acc[0] += a[q] * bf2f(v[q].x);
                acc[1] += a[q] * bf2f(v[q].y);
                acc[2] += a[q] * bf2f(v[q].z);
                acc[3] += a[q] * bf2f(v[q].w);
            }
        } else {
            ushort2 v[8];
#pragma unroll
            for (int q = 0; q < 8; ++q)
                v[q] = *reinterpret_cast<const ushort2*>(g + (size_t)s[q] * C + lane * 2);
#pragma unroll
            for (int q = 0; q < 8; ++q) {
                acc[0] += a[q] * bf2f(v[q].x);
                acc[1] += a[q] * bf2f(v[q].y);
            }
        }
    }
    for (; j < j1; ++j) {
        int s = csr_src[j];
        float a = csr_w[j];
        const ushort* hs = g + (size_t)s * C + lane * V;
        if constexpr (V == 4) {
            ushort4 v = *reinterpret_cast<const ushort4*>(hs);
            acc[0] += a * bf2f(v.x); acc[1] += a * bf2f(v.y);
            acc[2] += a * bf2f(v.z); acc[3] += a * bf2f(v.w);
        } else {
            ushort2 v = *reinterpret_cast<const ushort2*>(hs);
            acc[0] += a * bf2f(v.x); acc[1] += a * bf2f(v.y);
        }
    }
    const float* bp = bias + lane * V;
    ushort* op = out + (size_t)node * C + lane * V;
    if constexpr (V == 4) {
        float o0 = acc[0] * dn + bp[0], o1 = acc[1] * dn + bp[1];
        float o2 = acc[2] * dn + bp[2], o3 = acc[3] * dn + bp[3];
        if (RELU) { o0 = fmaxf(o0, 0.f); o1 = fmaxf(o1, 0.f); o2 = fmaxf(o2, 0.f); o3 = fmaxf(o3, 0.f); }
        ushort4 o;
        o.x = f2bf(o0); o.y = f2bf(o1); o.z = f2bf(o2); o.w = f2bf(o3);
        *reinterpret_cast<ushort4*>(op) = o;
        if constexpr (FUSE) {
            float4 wms = *reinterpret_cast<const float4*>(W_m1 + lane * 4);
            float4 wmd = *reinterpret_cast<const float4*>(W_m1 + C + lane * 4);
            float ms = o0 * wms.x + o1 * wms.y + o2 * wms.z + o3 * wms.w;
            float md = o0 * wmd.x + o1 * wmd.y + o2 * wmd.z + o3 * wmd.w;
#pragma unroll
            for (int off = 32; off > 0; off >>= 1) {
                ms += __shfl_down(ms, off, 64);
                md += __shfl_down(md, off, 64);
            }
            if (lane == 0) { m_s[node] = ms; m_d[node] = md; }
        }
    } else {
        float o0 = acc[0] * dn + bp[0], o1 = acc[1] * dn + bp[1];
        if (RELU) { o0 = fmaxf(o0, 0.f); o1 = fmaxf(o1, 0.f); }
        ushort2 o;
        o.x = f2bf(o0); o.y = f2bf(o1);
        *reinterpret_cast<ushort2*>(op) = o;
    }
}

// ---------------- final pairwise classifier on bf16 y1 = out2 @ W_f1 ----------------
__global__ __launch_bounds__(256) void final_edge(const ushort* __restrict__ y1,
                                                  const int* __restrict__ ea,
                                                  const int* __restrict__ eb,
                                                  const float* __restrict__ b_f1,
                                                  const float* __restrict__ W_f2,
                                                  const float* __restrict__ b_f2,
                                                  float* __restrict__ out, int E) {
    int lane = threadIdx.x & 63, wid = threadIdx.x >> 6;
    int sub = lane >> 3, k8 = lane & 7;
    int wave = blockIdx.x * 4 + wid;
    int e = wave * 8 + sub;
    if (e >= E) return;
    float4 bf1a = *reinterpret_cast<const float4*>(b_f1 + k8 * 8);
    float4 bf1b = *reinterpret_cast<const float4*>(b_f1 + k8 * 8 + 4);
    float4 wf2a = *reinterpret_cast<const float4*>(W_f2 + k8 * 8);
    float4 wf2b = *reinterpret_cast<const float4*>(W_f2 + k8 * 8 + 4);
    int a = ea[e], b = eb[e];
    ushortx8 va = *reinterpret_cast<const ushortx8*>(y1 + (size_t)a * 64 + k8 * 8);
    ushortx8 vb = *reinterpret_cast<const ushortx8*>(y1 + (size_t)b * 64 + k8 * 8);
    float p = fmaxf(bf2f(va.s0) - bf2f(vb.s0) + bf1a.x, 0.f) * wf2a.x
            + fmaxf(bf2f(va.s1) - bf2f(vb.s1) + bf1a.y, 0.f) * wf2a.y
            + fmaxf(bf2f(va.s2) - bf2f(vb.s2) + bf1a.z, 0.f) * wf2a.z
            + fmaxf(bf2f(va.s3) - bf2f(vb.s3) + bf1a.w, 0.f) * wf2a.w
            + fmaxf(bf2f(va.s4) - bf2f(vb.s4) + bf1b.x, 0.f) * wf2b.x
            + fmaxf(bf2f(va.s5) - bf2f(vb.s5) + bf1b.y, 0.f) * wf2b.y
            + fmaxf(bf2f(va.s6) - bf2f(vb.s6) + bf1b.z, 0.f) * wf2b.z
            + fmaxf(bf2f(va.s7) - bf2f(vb.s7) + bf1b.w, 0.f) * wf2b.w;
    p += __shfl_xor(p, 1, 64);
    p += __shfl_xor(p, 2, 64);
    p += __shfl_xor(p, 4, 64);
    if (k8 == 0) out[e] = 1.f / (1.f + expf(-(p + b_f2[0])));
}

extern "C" void kernel_launch(void* const* d_in, const int* in_sizes, int n_in,
                              void* d_out, int out_size, void* d_ws, size_t ws_size,
                              hipStream_t stream) {
    const float* x      = (const float*)d_in[0];
    const float* coords = (const float*)d_in[1];
    const float* W_app  = (const float*)d_in[2];
    const float* b_app  = (const float*)d_in[3];
    const float* W_geom = (const float*)d_in[4];
    const float* b_geom = (const float*)d_in[5];
    const float* W_aff  = (const float*)d_in[6];
    const float* b_aff  = (const float*)d_in[7];
    const float* W_c1   = (const float*)d_in[8];
    const float* b_c1   = (const float*)d_in[9];
    const float* W_m1   = (const float*)d_in[10];
    const float* b_m1   = (const float*)d_in[11];
    const float* W_c2   = (const float*)d_in[12];
    const float* b_c2   = (const float*)d_in[13];
    const float* W_f1   = (const float*)d_in[14];
    const float* b_f1   = (const float*)d_in[15];
    const float* W_f2   = (const float*)d_in[16];
    const float* b_f2   = (const float*)d_in[17];
    const int*   e1     = (const int*)d_in[18];
    const int*   e2     = (const int*)d_in[19];
    float* out = (float*)d_out;

    const int N = NN;
    const int E = NE;
    const int MP = 50048;  // 391*128
    const int* src1 = e1;
    const int* dst1 = e1 + E;
    const int* e2a = e2;
    const int* e2b = e2 + E;

    char* ws = (char*)d_ws;
    size_t off = 0;
    auto alloc = [&](size_t bytes) -> void* {
        void* p = ws + off;
        off += (bytes + 255) & ~(size_t)255;
        return p;
    };
    float* app_s  = (float*)alloc((size_t)N * 4);
    float* app_d  = (float*)alloc((size_t)N * 4);
    float* geo_s  = (float*)alloc((size_t)N * 4);
    float* geo_d  = (float*)alloc((size_t)N * 4);
    float* m_s    = (float*)alloc((size_t)N * 4);
    float* m_d    = (float*)alloc((size_t)N * 4);
    float* dinv1  = (float*)alloc((size_t)N * 4);
    float* dinv2  = (float*)alloc((size_t)N * 4);
    int* cursor   = (int*)alloc((size_t)N * 4);
    int* offsets  = (int*)alloc((size_t)(N + 1) * 4);
    int* btot     = (int*)alloc((size_t)64 * 4);
    int* rank     = (int*)alloc((size_t)E * 4);
    int* csr_src  = (int*)alloc((size_t)E * 4);
    float* csr_w  = (float*)alloc((size_t)E * 4);  // phase1 w, overwritten by phase2 w2
    ushort* wc1T  = (ushort*)alloc((size_t)256 * 512 * 2);
    ushort* wc2T  = (ushort*)alloc((size_t)128 * 256 * 2);
    ushort* wf1T  = (ushort*)alloc((size_t)64 * 128 * 2);
    ushort* x_bf  = (ushort*)alloc((size_t)MP * 512 * 2);  // 51.25 MB
    ushort* h_bf  = (ushort*)alloc((size_t)MP * 256 * 2);  // 25.62 MB
    // overlays:
    ushort* out1b = x_bf;                    // [MP][256] (x_bf dead after gemm1)
    ushort* h2b   = h_bf;                    // [N][128]  (h_bf dead after conv1)
    ushort* out2b = h_bf + (size_t)N * 128;  // [MP][128]
    ushort* y1b   = x_bf;                    // [MP][64]  (out1b dead after gemm2)

    int gN = (N + 255) / 256;
    int gE = (E + 255) / 256;
    int gW = (N + 3) / 4;
    int nb = (N + 1023) / 1024;   // 49

    hipMemsetAsync(cursor, 0, (size_t)N * 4, stream);
    prep_x<<<gW, 256, 0, stream>>>(x, W_app, coords, W_geom, x_bf, app_s, app_d,
                                   geo_s, geo_d, N);
    cvt_wT_all<<<672, 256, 0, stream>>>(W_c1, wc1T, W_c2, wc2T, W_f1, wf1T);

    // CSR build: one atomic pass, two-kernel scan, non-atomic place -> two streams
    scatter_rank<<<gE, 256, 0, stream>>>(dst1, cursor, rank, E);
    scanA<<<nb, 256, 0, stream>>>(cursor, btot, N);
    scanB<<<nb, 256, 0, stream>>>(cursor, btot, offsets, N, E);
    place_fused<<<gE, 256, 0, stream>>>(src1, dst1, rank, offsets, app_s, app_d, geo_s, geo_d,
                                        b_app, b_geom, W_aff, b_aff, csr_src, csr_w, E);
    deg_dinv<<<gN, 256, 0, stream>>>(csr_w, offsets, dinv1, N);

    // g1 = bf16(dinv1 ⊙ (x @ W_c1))
    mfma_gemm<2, 4, 4, true, true><<<dim3(MP / 128, 2), 256, 0, stream>>>(
        x_bf, wc1T, h_bf, dinv1, N, 256, 512);
    // out1b = relu(dn*(g1[n]+Σ w g1[src]) + b_c1) — wave/node, 8-deep; fused m dots
    conv_agg<256, true, true><<<gW, 256, 0, stream>>>(
        h_bf, dinv1, csr_src, csr_w, offsets, b_c1, out1b, W_m1, m_s, m_d, N);

    // phase-2 edge weights into csr_w + dinv2
    phase2_rows<<<gN, 256, 0, stream>>>(csr_src, csr_w, offsets, m_s, m_d, b_m1, dinv2, N);

    // g2 = bf16(dinv2 ⊙ (out1b @ W_c2))
    mfma_gemm<2, 4, 4, true, true><<<dim3(MP / 128, 1), 256, 0, stream>>>(
        out1b, wc2T, h2b, dinv2, N, 128, 256);
    // out2b = dn*(g2[n]+Σ w2 g2[src]) + b_c2 — wave/node
    conv_agg<128, false, false><<<gW, 256, 0, stream>>>(
        h2b, dinv2, csr_src, csr_w, offsets, b_c2, out2b, nullptr, nullptr, nullptr, N);

    // y1b = bf16(out2b @ W_f1)
    mfma_gemm<1, 2, 4, true, false><<<dim3(MP / 128, 1), 256, 0, stream>>>(
        out2b, wf1T, y1b, nullptr, N, 64, 128);

    // final pairwise classifier (8 lanes/edge)
    final_edge<<<E / 32, 256, 0, stream>>>(y1b, e2a, e2b, b_f1, W_f2, b_f2, out, E);
}